// Round 1
// baseline (1555.645 us; speedup 1.0000x reference)
//
#include <hip/hip_runtime.h>
#include <cstddef>

#define SDN 16      // state dim
#define DIN 64      // input dim
#define DOUT 64     // output dim
#define NBATCH 32
#define SEQL 8192
#define CHUNK 128   // main timesteps per block
#define WARM 64     // warmup timesteps (A^64 ~ 1e-10 => state converged)
#define TTOT (CHUNK + WARM)   // 192
#define UBLK 8                // scan blocking factor
#define NWIN (TTOT / UBLK)    // 24 windows
#define MAINW (CHUNK / UBLK)  // 16 main windows
#define NCHUNK (SEQL / CHUNK) // 64
#define BLK 512

// workspace layout (floats)
#define WS_AD 0
#define WS_A8 256
#define WS_AP 512      // Ap[j], j=0..7, each 256
#define WS_BD 2560     // 16*64
#define WS_TOT 3584

// ---------------- setup: discretize the tiny 16x16 system ----------------
__global__ __launch_bounds__(256) void setup_kernel(
    const float* __restrict__ ll, const float* __restrict__ p,
    const float* __restrict__ q, const float* __restrict__ Bg,
    const float* __restrict__ Pg, float* __restrict__ ws)
{
  __shared__ float Lam[SDN], pv[SDN], qv[SDN];
  __shared__ float core[SDN][SDN], T1[SDN][SDN], Ac[SDN][SDN];
  __shared__ float aug[SDN][2 * SDN];
  __shared__ float Ap[UBLK + 1][SDN][SDN];
  __shared__ float Ad[SDN][SDN];
  __shared__ float Bd[SDN][DIN];
  const int tid = threadIdx.x;
  const int i = tid >> 4, j = tid & 15;

  if (tid < SDN) { Lam[tid] = -expf(ll[tid]); pv[tid] = p[tid]; qv[tid] = q[tid]; }
  __syncthreads();
  core[i][j] = (i == j ? Lam[i] : 0.f) + pv[i] * qv[j];
  __syncthreads();
  {
    float acc = 0.f;
    for (int k = 0; k < SDN; ++k) acc += Pg[i * SDN + k] * core[k][j];
    T1[i][j] = acc;
  }
  __syncthreads();
  {
    float acc = 0.f;
    for (int k = 0; k < SDN; ++k) acc += T1[i][k] * Pg[j * SDN + k];
    Ac[i][j] = acc;
  }
  __syncthreads();
  for (int s = tid; s < SDN * 2 * SDN; s += 256) {
    int ii = s >> 5, jj = s & 31;
    aug[ii][jj] = (jj < SDN) ? ((ii == jj ? 1.f : 0.f) - 0.5f * Ac[ii][jj])
                             : ((ii == (jj - SDN)) ? 1.f : 0.f);
  }
  __syncthreads();
  // Gauss-Jordan (I - A/2 is diagonally dominant; no pivoting needed)
  for (int k = 0; k < SDN; ++k) {
    float pinv = 1.0f / aug[k][k];
    __syncthreads();
    if (tid < 2 * SDN) aug[k][tid] *= pinv;
    __syncthreads();
    int i0 = tid >> 5, j0 = tid & 31;
    int i1 = (tid + 256) >> 5, j1 = (tid + 256) & 31;
    float f0 = aug[i0][k], f1 = aug[i1][k];
    __syncthreads();
    if (i0 != k) aug[i0][j0] -= f0 * aug[k][j0];
    if (i1 != k) aug[i1][j1] -= f1 * aug[k][j1];
    __syncthreads();
  }
  // A_d = Minv * (I + A/2)
  {
    float acc = 0.f;
    for (int k = 0; k < SDN; ++k)
      acc += aug[i][SDN + k] * ((k == j ? 1.f : 0.f) + 0.5f * Ac[k][j]);
    Ad[i][j] = acc;
  }
  // B_d = Minv * B   (DT = 1)
  for (int s = tid; s < SDN * DIN; s += 256) {
    int n = s >> 6, d = s & 63;
    float acc = 0.f;
    for (int k = 0; k < SDN; ++k) acc += aug[n][SDN + k] * Bg[k * DIN + d];
    Bd[n][d] = acc;
  }
  Ap[0][i][j] = (i == j) ? 1.f : 0.f;
  __syncthreads();
  for (int jj = 1; jj <= UBLK; ++jj) {
    float acc = 0.f;
    for (int k = 0; k < SDN; ++k) acc += Ap[jj - 1][i][k] * Ad[k][j];
    Ap[jj][i][j] = acc;
    __syncthreads();
  }
  ws[WS_AD + tid] = Ad[i][j];
  ws[WS_A8 + tid] = Ap[UBLK][i][j];
  for (int jj = 0; jj < UBLK; ++jj) ws[WS_AP + jj * 256 + tid] = Ap[jj][i][j];
  for (int s = tid; s < SDN * DIN; s += 256) ws[WS_BD + s] = (&Bd[0][0])[s];
}

// ---------------- main: per-(batch, chunk) warmup scan + outputs ----------------
struct SM {
  float u[TTOT][SDN + 1];          // B_d x_t
  float ht[CHUNK][SDN + 1];        // reconstructed states (main region)
  float v[NWIN][SDN + 1];          // window-aggregated inputs
  float H[NWIN][SDN + 1];          // state at window boundaries
  float Ad[SDN][SDN + 1];
  float A8[SDN][SDN + 1];
  float Ap[UBLK][SDN][SDN + 1];
  float4 Bd[SDN][DIN / 4 + 1];     // rows of 68 floats (16B aligned)
  float4 CT[SDN][DOUT / 4];        // CT[n][o4] = C[o][n]
  float4 DT[DIN][DOUT / 4];        // DT[d][o4] = D[o][d]
};

__global__ __launch_bounds__(BLK, 4) void main_kernel(
    const float* __restrict__ x, const float* __restrict__ Cg,
    const float* __restrict__ Dg, const float* __restrict__ ws,
    float* __restrict__ y)
{
  __shared__ SM sm;
  const int tid = threadIdx.x;
  const int c = blockIdx.x & (NCHUNK - 1);
  const int b = blockIdx.x >> 6;
  const int t0 = c * CHUNK;
  const int g0 = t0 - WARM;

  // load constant matrices into LDS
  for (int s = tid; s < 256; s += BLK) {
    sm.Ad[s >> 4][s & 15] = ws[WS_AD + s];
    sm.A8[s >> 4][s & 15] = ws[WS_A8 + s];
  }
  for (int s = tid; s < UBLK * 256; s += BLK) {
    int jj = s >> 8, r = s & 255;
    sm.Ap[jj][r >> 4][r & 15] = ws[WS_AP + s];
  }
  for (int s = tid; s < SDN * DIN; s += BLK) {
    int n = s >> 6, d = s & 63;
    ((float*)&sm.Bd[n][0])[d] = ws[WS_BD + s];
  }
  for (int s = tid; s < DOUT * SDN; s += BLK) {     // C is (64,16) row-major
    int o = s >> 4, n = s & 15;
    ((float*)&sm.CT[n][0])[o] = Cg[s];
  }
  for (int s = tid; s < DOUT * DIN; s += BLK) {     // D is (64,64) row-major
    int o = s >> 6, d = s & 63;
    ((float*)&sm.DT[d][0])[o] = Dg[s];
  }
  __syncthreads();

  // phase a1: u[tt][n] = B_d x_t  for tt in [0,192)
  {
    const int n = tid & 15, ttb = tid >> 4;  // 32 rows per pass
    for (int base = 0; base < TTOT; base += 32) {
      int tt = base + ttb;
      int t = g0 + tt;
      float acc = 0.f;
      if (t >= 0) {
        const float4* xr = (const float4*)(x + ((size_t)b * SEQL + t) * DIN);
        #pragma unroll
        for (int dd = 0; dd < DIN / 4; ++dd) {
          float4 xv = xr[dd];
          float4 bv = sm.Bd[n][dd];
          acc += xv.x * bv.x + xv.y * bv.y + xv.z * bv.z + xv.w * bv.w;
        }
      }
      sm.u[tt][n] = acc;
    }
  }
  __syncthreads();

  // phase a2: v[w] = sum_j A^(7-j) u[w*8+j]
  if (tid < NWIN * SDN) {
    int w = tid >> 4, n = tid & 15;
    float acc = 0.f;
    #pragma unroll
    for (int jj = 0; jj < UBLK; ++jj) {
      const float* ap = sm.Ap[UBLK - 1 - jj][n];
      const float* ur = sm.u[w * UBLK + jj];
      #pragma unroll
      for (int m = 0; m < SDN; ++m) acc += ap[m] * ur[m];
    }
    sm.v[w][n] = acc;
  }
  __syncthreads();

  // phase b: serial scan over 24 windows, wave 0 only, h in registers
  if (tid < 64) {
    const int n = tid & 15;
    float a8r[SDN];
    #pragma unroll
    for (int m = 0; m < SDN; ++m) a8r[m] = sm.A8[n][m];
    float h = 0.f;
    for (int w = 0; w < NWIN; ++w) {
      float acc = sm.v[w][n];
      #pragma unroll
      for (int m = 0; m < SDN; ++m) acc += a8r[m] * __shfl(h, m, 64);
      h = acc;
      if (tid < 16) sm.H[w][n] = h;
    }
  }
  __syncthreads();

  // phase c: reconstruct per-t states for the main region
  for (int jj = 0; jj < UBLK; ++jj) {
    if (tid < MAINW * SDN) {
      int wl = tid >> 4, n = tid & 15;
      int idx = wl * UBLK + jj;
      const float* hp = (jj == 0) ? sm.H[WARM / UBLK - 1 + wl] : sm.ht[idx - 1];
      const float* ar = sm.Ad[n];
      float acc = sm.u[WARM + idx][n];
      #pragma unroll
      for (int m = 0; m < SDN; ++m) acc += ar[m] * hp[m];
      sm.ht[idx][n] = acc;
    }
    __syncthreads();
  }

  // phase d: y[t][o] = C h_t + D x_t, float4 outputs
  {
    const int og = tid & 15, trb = tid >> 4;  // 32 t-rows per pass
    for (int base = 0; base < CHUNK; base += 32) {
      int tl = base + trb;
      int t = t0 + tl;
      const float* hr = sm.ht[tl];
      float4 acc = make_float4(0.f, 0.f, 0.f, 0.f);
      #pragma unroll
      for (int n = 0; n < SDN; ++n) {
        float hn = hr[n];
        float4 cv = sm.CT[n][og];
        acc.x += hn * cv.x; acc.y += hn * cv.y;
        acc.z += hn * cv.z; acc.w += hn * cv.w;
      }
      const float4* xr = (const float4*)(x + ((size_t)b * SEQL + t) * DIN);
      #pragma unroll
      for (int dd = 0; dd < DIN / 4; ++dd) {
        float4 xv = xr[dd];
        float4 d0 = sm.DT[dd * 4 + 0][og];
        float4 d1 = sm.DT[dd * 4 + 1][og];
        float4 d2 = sm.DT[dd * 4 + 2][og];
        float4 d3 = sm.DT[dd * 4 + 3][og];
        acc.x += xv.x * d0.x + xv.y * d1.x + xv.z * d2.x + xv.w * d3.x;
        acc.y += xv.x * d0.y + xv.y * d1.y + xv.z * d2.y + xv.w * d3.y;
        acc.z += xv.x * d0.z + xv.y * d1.z + xv.z * d2.z + xv.w * d3.z;
        acc.w += xv.x * d0.w + xv.y * d1.w + xv.z * d2.w + xv.w * d3.w;
      }
      ((float4*)(y + ((size_t)b * SEQL + t) * DOUT))[og] = acc;
    }
  }
}

extern "C" void kernel_launch(void* const* d_in, const int* in_sizes, int n_in,
                              void* d_out, int out_size, void* d_ws, size_t ws_size,
                              hipStream_t stream) {
  const float* x  = (const float*)d_in[0];
  const float* ll = (const float*)d_in[1];
  const float* p  = (const float*)d_in[2];
  const float* q  = (const float*)d_in[3];
  const float* B  = (const float*)d_in[4];
  const float* C  = (const float*)d_in[5];
  const float* D  = (const float*)d_in[6];
  const float* P  = (const float*)d_in[7];
  float* yo = (float*)d_out;
  float* ws = (float*)d_ws;
  setup_kernel<<<1, 256, 0, stream>>>(ll, p, q, B, P, ws);
  main_kernel<<<NBATCH * NCHUNK, BLK, 0, stream>>>(x, C, D, ws, yo);
}

// Round 5
// 830.203 us; speedup vs baseline: 1.8738x; 1.8738x over previous
//
#include <hip/hip_runtime.h>
#include <cstddef>

#define SDN 16      // state dim
#define DIN 64      // input dim
#define DOUT 64     // output dim
#define NBATCH 32
#define SEQL 8192
#define CHUNK 128   // main timesteps per block
#define WARM 64     // warmup timesteps (A^64 ~ 1e-10 => state converged)
#define TTOT (CHUNK + WARM)   // 192
#define UBLK 8                // scan blocking factor
#define NWIN (TTOT / UBLK)    // 24 windows
#define MAINW (CHUNK / UBLK)  // 16 main windows
#define NCHUNK (SEQL / CHUNK) // 64
#define BLK 512

// workspace layout (floats)
#define WS_AD 0
#define WS_A8 256
#define WS_AP 512      // Ap[j], j=0..7, each 256
#define WS_BD 2560     // 16*64
#define WS_TOT 3584

// ---------------- setup: discretize the tiny 16x16 system ----------------
__global__ __launch_bounds__(256) void setup_kernel(
    const float* __restrict__ ll, const float* __restrict__ p,
    const float* __restrict__ q, const float* __restrict__ Bg,
    const float* __restrict__ Pg, float* __restrict__ ws)
{
  __shared__ float Lam[SDN], pv[SDN], qv[SDN];
  __shared__ float core[SDN][SDN], T1[SDN][SDN], Ac[SDN][SDN];
  __shared__ float aug[SDN][2 * SDN];
  __shared__ float Ap[UBLK + 1][SDN][SDN];
  __shared__ float Ad[SDN][SDN];
  __shared__ float Bd[SDN][DIN];
  const int tid = threadIdx.x;
  const int i = tid >> 4, j = tid & 15;

  if (tid < SDN) { Lam[tid] = -expf(ll[tid]); pv[tid] = p[tid]; qv[tid] = q[tid]; }
  __syncthreads();
  core[i][j] = (i == j ? Lam[i] : 0.f) + pv[i] * qv[j];
  __syncthreads();
  {
    float acc = 0.f;
    for (int k = 0; k < SDN; ++k) acc += Pg[i * SDN + k] * core[k][j];
    T1[i][j] = acc;
  }
  __syncthreads();
  {
    float acc = 0.f;
    for (int k = 0; k < SDN; ++k) acc += T1[i][k] * Pg[j * SDN + k];
    Ac[i][j] = acc;
  }
  __syncthreads();
  for (int s = tid; s < SDN * 2 * SDN; s += 256) {
    int ii = s >> 5, jj = s & 31;
    aug[ii][jj] = (jj < SDN) ? ((ii == jj ? 1.f : 0.f) - 0.5f * Ac[ii][jj])
                             : ((ii == (jj - SDN)) ? 1.f : 0.f);
  }
  __syncthreads();
  // Gauss-Jordan (I - A/2 is diagonally dominant; no pivoting needed)
  for (int k = 0; k < SDN; ++k) {
    float pinv = 1.0f / aug[k][k];
    __syncthreads();
    if (tid < 2 * SDN) aug[k][tid] *= pinv;
    __syncthreads();
    int i0 = tid >> 5, j0 = tid & 31;
    int i1 = (tid + 256) >> 5, j1 = (tid + 256) & 31;
    float f0 = aug[i0][k], f1 = aug[i1][k];
    __syncthreads();
    if (i0 != k) aug[i0][j0] -= f0 * aug[k][j0];
    if (i1 != k) aug[i1][j1] -= f1 * aug[k][j1];
    __syncthreads();
  }
  // A_d = Minv * (I + A/2)
  {
    float acc = 0.f;
    for (int k = 0; k < SDN; ++k)
      acc += aug[i][SDN + k] * ((k == j ? 1.f : 0.f) + 0.5f * Ac[k][j]);
    Ad[i][j] = acc;
  }
  // B_d = Minv * B   (DT = 1)
  for (int s = tid; s < SDN * DIN; s += 256) {
    int n = s >> 6, d = s & 63;
    float acc = 0.f;
    for (int k = 0; k < SDN; ++k) acc += aug[n][SDN + k] * Bg[k * DIN + d];
    Bd[n][d] = acc;
  }
  Ap[0][i][j] = (i == j) ? 1.f : 0.f;
  __syncthreads();
  for (int jj = 1; jj <= UBLK; ++jj) {
    float acc = 0.f;
    for (int k = 0; k < SDN; ++k) acc += Ap[jj - 1][i][k] * Ad[k][j];
    Ap[jj][i][j] = acc;
    __syncthreads();
  }
  ws[WS_AD + tid] = Ad[i][j];
  ws[WS_A8 + tid] = Ap[UBLK][i][j];
  for (int jj = 0; jj < UBLK; ++jj) ws[WS_AP + jj * 256 + tid] = Ap[jj][i][j];
  for (int s = tid; s < SDN * DIN; s += 256) ws[WS_BD + s] = (&Bd[0][0])[s];
}

// ---------------- main: per-(batch, chunk) warmup scan + outputs ----------------
// x is staged to LDS ONCE with a linear coalesced pattern; all reuse
// (B_d*x and D*x) is served from LDS broadcast reads.
#define XPAD 68   // 17 float4 per row: 16B-aligned, rows start 4 banks apart

struct SM {
  float xs[TTOT][XPAD];            // staged x rows (52224 B)
  float u[TTOT][SDN + 1];          // B_d x_t
  float ht[CHUNK][SDN + 1];        // reconstructed states (main region)
  float v[NWIN][SDN + 1];          // window-aggregated inputs
  float H[NWIN][SDN + 1];          // state at window boundaries
  float Ad[SDN][SDN + 1];
  float A8[SDN][SDN + 1];
  float Ap[UBLK][SDN][SDN + 1];
  float4 Bd[SDN][DIN / 4 + 1];
  float4 CT[SDN][DOUT / 4];        // CT[n][o4] = C[o][n]
  float4 DT[DIN][DOUT / 4];        // DT[d][o4] = D[o][d]
};

__global__ __launch_bounds__(BLK) void main_kernel(
    const float* __restrict__ x, const float* __restrict__ Cg,
    const float* __restrict__ Dg, const float* __restrict__ ws,
    float* __restrict__ y)
{
  __shared__ SM sm;
  const int tid = threadIdx.x;
  const int c = blockIdx.x & (NCHUNK - 1);
  const int b = blockIdx.x >> 6;
  const int t0 = c * CHUNK;
  const int g0 = t0 - WARM;

  // ---- stage x: fully linear, coalesced (512 thr x float4 = 8KiB/step) ----
  {
    const float4* xg = (const float4*)(x + (size_t)b * SEQL * DIN);
    #pragma unroll
    for (int s = tid; s < TTOT * 16; s += BLK) {
      int tt = s >> 4, d4 = s & 15;
      int t = g0 + tt;
      float4 xv = make_float4(0.f, 0.f, 0.f, 0.f);
      if (t >= 0) xv = xg[t * 16 + d4];
      ((float4*)&sm.xs[tt][0])[d4] = xv;
    }
  }

  // load constant matrices into LDS
  for (int s = tid; s < 256; s += BLK) {
    sm.Ad[s >> 4][s & 15] = ws[WS_AD + s];
    sm.A8[s >> 4][s & 15] = ws[WS_A8 + s];
  }
  for (int s = tid; s < UBLK * 256; s += BLK) {
    int jj = s >> 8, r = s & 255;
    sm.Ap[jj][r >> 4][r & 15] = ws[WS_AP + s];
  }
  for (int s = tid; s < SDN * DIN; s += BLK) {
    int n = s >> 6, d = s & 63;
    ((float*)&sm.Bd[n][0])[d] = ws[WS_BD + s];
  }
  for (int s = tid; s < DOUT * SDN; s += BLK) {     // C is (64,16) row-major
    int o = s >> 4, n = s & 15;
    ((float*)&sm.CT[n][0])[o] = Cg[s];
  }
  for (int s = tid; s < DOUT * DIN; s += BLK) {     // D is (64,64) row-major
    int o = s >> 6, d = s & 63;
    ((float*)&sm.DT[d][0])[o] = Dg[s];
  }
  __syncthreads();

  // phase a1: u[tt][n] = B_d x_t  (x from LDS broadcast)
  {
    const int n = tid & 15, ttb = tid >> 4;  // 32 rows per pass
    for (int base = 0; base < TTOT; base += 32) {
      int tt = base + ttb;
      const float4* xr = (const float4*)&sm.xs[tt][0];
      float acc = 0.f;
      #pragma unroll
      for (int dd = 0; dd < DIN / 4; ++dd) {
        float4 xv = xr[dd];
        float4 bv = sm.Bd[n][dd];
        acc += xv.x * bv.x + xv.y * bv.y + xv.z * bv.z + xv.w * bv.w;
      }
      sm.u[tt][n] = acc;
    }
  }
  __syncthreads();

  // phase a2: v[w] = sum_j A^(7-j) u[w*8+j]
  if (tid < NWIN * SDN) {
    int w = tid >> 4, n = tid & 15;
    float acc = 0.f;
    #pragma unroll
    for (int jj = 0; jj < UBLK; ++jj) {
      const float* ap = sm.Ap[UBLK - 1 - jj][n];
      const float* ur = sm.u[w * UBLK + jj];
      #pragma unroll
      for (int m = 0; m < SDN; ++m) acc += ap[m] * ur[m];
    }
    sm.v[w][n] = acc;
  }
  __syncthreads();

  // phase b: serial scan over 24 windows, wave 0 only, h in registers
  if (tid < 64) {
    const int n = tid & 15;
    float a8r[SDN];
    #pragma unroll
    for (int m = 0; m < SDN; ++m) a8r[m] = sm.A8[n][m];
    float h = 0.f;
    for (int w = 0; w < NWIN; ++w) {
      float acc = sm.v[w][n];
      #pragma unroll
      for (int m = 0; m < SDN; ++m) acc += a8r[m] * __shfl(h, m, 64);
      h = acc;
      if (tid < 16) sm.H[w][n] = h;
    }
  }
  __syncthreads();

  // phase c: reconstruct per-t states for the main region
  for (int jj = 0; jj < UBLK; ++jj) {
    if (tid < MAINW * SDN) {
      int wl = tid >> 4, n = tid & 15;
      int idx = wl * UBLK + jj;
      const float* hp = (jj == 0) ? sm.H[WARM / UBLK - 1 + wl] : sm.ht[idx - 1];
      const float* ar = sm.Ad[n];
      float acc = sm.u[WARM + idx][n];
      #pragma unroll
      for (int m = 0; m < SDN; ++m) acc += ar[m] * hp[m];
      sm.ht[idx][n] = acc;
    }
    __syncthreads();
  }

  // phase d: y[t][o] = C h_t + D x_t  (x from LDS), float4 coalesced stores
  {
    const int og = tid & 15, trb = tid >> 4;  // 32 t-rows per pass
    for (int base = 0; base < CHUNK; base += 32) {
      int tl = base + trb;
      int t = t0 + tl;
      const float* hr = sm.ht[tl];
      float4 acc = make_float4(0.f, 0.f, 0.f, 0.f);
      #pragma unroll
      for (int n = 0; n < SDN; ++n) {
        float hn = hr[n];
        float4 cv = sm.CT[n][og];
        acc.x += hn * cv.x; acc.y += hn * cv.y;
        acc.z += hn * cv.z; acc.w += hn * cv.w;
      }
      const float4* xr = (const float4*)&sm.xs[WARM + tl][0];
      #pragma unroll
      for (int dd = 0; dd < DIN / 4; ++dd) {
        float4 xv = xr[dd];
        float4 d0 = sm.DT[dd * 4 + 0][og];
        float4 d1 = sm.DT[dd * 4 + 1][og];
        float4 d2 = sm.DT[dd * 4 + 2][og];
        float4 d3 = sm.DT[dd * 4 + 3][og];
        acc.x += xv.x * d0.x + xv.y * d1.x + xv.z * d2.x + xv.w * d3.x;
        acc.y += xv.x * d0.y + xv.y * d1.y + xv.z * d2.y + xv.w * d3.y;
        acc.z += xv.x * d0.z + xv.y * d1.z + xv.z * d2.z + xv.w * d3.z;
        acc.w += xv.x * d0.w + xv.y * d1.w + xv.z * d2.w + xv.w * d3.w;
      }
      ((float4*)(y + ((size_t)b * SEQL + t) * DOUT))[og] = acc;
    }
  }
}

extern "C" void kernel_launch(void* const* d_in, const int* in_sizes, int n_in,
                              void* d_out, int out_size, void* d_ws, size_t ws_size,
                              hipStream_t stream) {
  const float* x  = (const float*)d_in[0];
  const float* ll = (const float*)d_in[1];
  const float* p  = (const float*)d_in[2];
  const float* q  = (const float*)d_in[3];
  const float* B  = (const float*)d_in[4];
  const float* C  = (const float*)d_in[5];
  const float* D  = (const float*)d_in[6];
  const float* P  = (const float*)d_in[7];
  float* yo = (float*)d_out;
  float* ws = (float*)d_ws;
  setup_kernel<<<1, 256, 0, stream>>>(ll, p, q, B, P, ws);
  main_kernel<<<NBATCH * NCHUNK, BLK, 0, stream>>>(x, C, D, ws, yo);
}

// Round 7
// 310.198 us; speedup vs baseline: 5.0150x; 2.6764x over previous
//
#include <hip/hip_runtime.h>
#include <cstddef>

#define SDN 16      // state dim
#define DIN 64      // input dim
#define DOUT 64     // output dim
#define NBATCH 32
#define SEQL 8192
#define CHUNK 128   // main timesteps per block
#define WARM 64     // warmup timesteps (A^64 ~ 1e-10 => state converged)
#define TTOT (CHUNK + WARM)   // 192
#define UBLK 8                // scan blocking factor
#define NWIN (TTOT / UBLK)    // 24 windows
#define MAINW (CHUNK / UBLK)  // 16 main windows
#define NCHUNK (SEQL / CHUNK) // 64
#define BLK 512

// workspace layout (floats)
#define WS_AD 0
#define WS_A8 256
#define WS_AP 512      // Ap[j], j=0..7, each 256
#define WS_BD 2560     // 16*64
#define WS_TOT 3584

// ---------------- setup: discretize the tiny 16x16 system ----------------
__global__ __launch_bounds__(256) void setup_kernel(
    const float* __restrict__ ll, const float* __restrict__ p,
    const float* __restrict__ q, const float* __restrict__ Bg,
    const float* __restrict__ Pg, float* __restrict__ ws)
{
  __shared__ float Lam[SDN], pv[SDN], qv[SDN];
  __shared__ float core[SDN][SDN], T1[SDN][SDN], Ac[SDN][SDN];
  __shared__ float aug[SDN][2 * SDN];
  __shared__ float Ap[UBLK + 1][SDN][SDN];
  __shared__ float Ad[SDN][SDN];
  __shared__ float Bd[SDN][DIN];
  const int tid = threadIdx.x;
  const int i = tid >> 4, j = tid & 15;

  if (tid < SDN) { Lam[tid] = -expf(ll[tid]); pv[tid] = p[tid]; qv[tid] = q[tid]; }
  __syncthreads();
  core[i][j] = (i == j ? Lam[i] : 0.f) + pv[i] * qv[j];
  __syncthreads();
  {
    float acc = 0.f;
    for (int k = 0; k < SDN; ++k) acc += Pg[i * SDN + k] * core[k][j];
    T1[i][j] = acc;
  }
  __syncthreads();
  {
    float acc = 0.f;
    for (int k = 0; k < SDN; ++k) acc += T1[i][k] * Pg[j * SDN + k];
    Ac[i][j] = acc;
  }
  __syncthreads();
  for (int s = tid; s < SDN * 2 * SDN; s += 256) {
    int ii = s >> 5, jj = s & 31;
    aug[ii][jj] = (jj < SDN) ? ((ii == jj ? 1.f : 0.f) - 0.5f * Ac[ii][jj])
                             : ((ii == (jj - SDN)) ? 1.f : 0.f);
  }
  __syncthreads();
  // Gauss-Jordan (I - A/2 is diagonally dominant; no pivoting needed)
  for (int k = 0; k < SDN; ++k) {
    float pinv = 1.0f / aug[k][k];
    __syncthreads();
    if (tid < 2 * SDN) aug[k][tid] *= pinv;
    __syncthreads();
    int i0 = tid >> 5, j0 = tid & 31;
    int i1 = (tid + 256) >> 5, j1 = (tid + 256) & 31;
    float f0 = aug[i0][k], f1 = aug[i1][k];
    __syncthreads();
    if (i0 != k) aug[i0][j0] -= f0 * aug[k][j0];
    if (i1 != k) aug[i1][j1] -= f1 * aug[k][j1];
    __syncthreads();
  }
  // A_d = Minv * (I + A/2)
  {
    float acc = 0.f;
    for (int k = 0; k < SDN; ++k)
      acc += aug[i][SDN + k] * ((k == j ? 1.f : 0.f) + 0.5f * Ac[k][j]);
    Ad[i][j] = acc;
  }
  // B_d = Minv * B   (DT = 1)
  for (int s = tid; s < SDN * DIN; s += 256) {
    int n = s >> 6, d = s & 63;
    float acc = 0.f;
    for (int k = 0; k < SDN; ++k) acc += aug[n][SDN + k] * Bg[k * DIN + d];
    Bd[n][d] = acc;
  }
  Ap[0][i][j] = (i == j) ? 1.f : 0.f;
  __syncthreads();
  for (int jj = 1; jj <= UBLK; ++jj) {
    float acc = 0.f;
    for (int k = 0; k < SDN; ++k) acc += Ap[jj - 1][i][k] * Ad[k][j];
    Ap[jj][i][j] = acc;
    __syncthreads();
  }
  ws[WS_AD + tid] = Ad[i][j];
  ws[WS_A8 + tid] = Ap[UBLK][i][j];
  for (int jj = 0; jj < UBLK; ++jj) ws[WS_AP + jj * 256 + tid] = Ap[jj][i][j];
  for (int s = tid; s < SDN * DIN; s += 256) ws[WS_BD + s] = (&Bd[0][0])[s];
}

// ---------------- main: per-(batch, chunk) warmup scan + outputs ----------------
// x is staged to LDS ONCE (linear coalesced); all reuse from LDS.
// LDS limits us to 1 block/CU (8 waves = 2 waves/EU), so launch_bounds(512,2)
// legitimately grants a 256-VGPR budget -> no scratch spill. Outer row loops
// are kept rolled (unroll 1) and inner dd loops partially unrolled (4) to cap
// the hoisted-LDS-load register pressure that was spilling in r1/r5.
#define XPAD 68   // 17 float4 per row: 16B-aligned, rows start 4 banks apart

struct SM {
  float xs[TTOT][XPAD];            // staged x rows (52224 B)
  float u[TTOT][SDN + 1];          // B_d x_t
  float ht[CHUNK][SDN + 1];        // reconstructed states (main region)
  float v[NWIN][SDN + 1];          // window-aggregated inputs
  float H[NWIN][SDN + 1];          // state at window boundaries
  float Ad[SDN][SDN + 1];
  float A8[SDN][SDN + 1];
  float Ap[UBLK][SDN][SDN + 1];
  float4 Bd[SDN][DIN / 4 + 1];
  float4 CT[SDN][DOUT / 4];        // CT[n][o4] = C[o][n]
  float4 DT[DIN][DOUT / 4];        // DT[d][o4] = D[o][d]
};

__global__ __launch_bounds__(BLK, 2) void main_kernel(
    const float* __restrict__ x, const float* __restrict__ Cg,
    const float* __restrict__ Dg, const float* __restrict__ ws,
    float* __restrict__ y)
{
  __shared__ SM sm;
  const int tid = threadIdx.x;
  const int c = blockIdx.x & (NCHUNK - 1);
  const int b = blockIdx.x >> 6;
  const int t0 = c * CHUNK;
  const int g0 = t0 - WARM;

  // ---- stage x: fully linear, coalesced (512 thr x float4 = 8KiB/step) ----
  {
    const float4* xg = (const float4*)(x + (size_t)b * SEQL * DIN);
    for (int s = tid; s < TTOT * 16; s += BLK) {
      int tt = s >> 4, d4 = s & 15;
      int t = g0 + tt;
      float4 xv = make_float4(0.f, 0.f, 0.f, 0.f);
      if (t >= 0) xv = xg[t * 16 + d4];
      ((float4*)&sm.xs[tt][0])[d4] = xv;
    }
  }

  // load constant matrices into LDS
  for (int s = tid; s < 256; s += BLK) {
    sm.Ad[s >> 4][s & 15] = ws[WS_AD + s];
    sm.A8[s >> 4][s & 15] = ws[WS_A8 + s];
  }
  for (int s = tid; s < UBLK * 256; s += BLK) {
    int jj = s >> 8, r = s & 255;
    sm.Ap[jj][r >> 4][r & 15] = ws[WS_AP + s];
  }
  for (int s = tid; s < SDN * DIN; s += BLK) {
    int n = s >> 6, d = s & 63;
    ((float*)&sm.Bd[n][0])[d] = ws[WS_BD + s];
  }
  for (int s = tid; s < DOUT * SDN; s += BLK) {     // C is (64,16) row-major
    int o = s >> 4, n = s & 15;
    ((float*)&sm.CT[n][0])[o] = Cg[s];
  }
  for (int s = tid; s < DOUT * DIN; s += BLK) {     // D is (64,64) row-major
    int o = s >> 6, d = s & 63;
    ((float*)&sm.DT[d][0])[o] = Dg[s];
  }
  __syncthreads();

  // phase a1: u[tt][n] = B_d x_t  (x from LDS broadcast)
  {
    const int n = tid & 15, ttb = tid >> 4;  // 32 rows per pass
    #pragma unroll 1
    for (int base = 0; base < TTOT; base += 32) {
      int tt = base + ttb;
      const float4* xr = (const float4*)&sm.xs[tt][0];
      float acc = 0.f;
      #pragma unroll 4
      for (int dd = 0; dd < DIN / 4; ++dd) {
        float4 xv = xr[dd];
        float4 bv = sm.Bd[n][dd];
        acc += xv.x * bv.x + xv.y * bv.y + xv.z * bv.z + xv.w * bv.w;
      }
      sm.u[tt][n] = acc;
    }
  }
  __syncthreads();

  // phase a2: v[w] = sum_j A^(7-j) u[w*8+j]
  if (tid < NWIN * SDN) {
    int w = tid >> 4, n = tid & 15;
    float acc = 0.f;
    #pragma unroll 2
    for (int jj = 0; jj < UBLK; ++jj) {
      const float* ap = sm.Ap[UBLK - 1 - jj][n];
      const float* ur = sm.u[w * UBLK + jj];
      #pragma unroll
      for (int m = 0; m < SDN; ++m) acc += ap[m] * ur[m];
    }
    sm.v[w][n] = acc;
  }
  __syncthreads();

  // phase b: serial scan over 24 windows, wave 0 only, h in registers
  if (tid < 64) {
    const int n = tid & 15;
    float a8r[SDN];
    #pragma unroll
    for (int m = 0; m < SDN; ++m) a8r[m] = sm.A8[n][m];
    float h = 0.f;
    for (int w = 0; w < NWIN; ++w) {
      float acc = sm.v[w][n];
      #pragma unroll
      for (int m = 0; m < SDN; ++m) acc += a8r[m] * __shfl(h, m, 64);
      h = acc;
      if (tid < 16) sm.H[w][n] = h;
    }
  }
  __syncthreads();

  // phase c: reconstruct per-t states for the main region
  #pragma unroll 1
  for (int jj = 0; jj < UBLK; ++jj) {
    if (tid < MAINW * SDN) {
      int wl = tid >> 4, n = tid & 15;
      int idx = wl * UBLK + jj;
      const float* hp = (jj == 0) ? sm.H[WARM / UBLK - 1 + wl] : sm.ht[idx - 1];
      const float* ar = sm.Ad[n];
      float acc = sm.u[WARM + idx][n];
      #pragma unroll
      for (int m = 0; m < SDN; ++m) acc += ar[m] * hp[m];
      sm.ht[idx][n] = acc;
    }
    __syncthreads();
  }

  // phase d: y[t][o] = C h_t + D x_t  (x from LDS), float4 coalesced stores
  {
    const int og = tid & 15, trb = tid >> 4;  // 32 t-rows per pass
    #pragma unroll 1
    for (int base = 0; base < CHUNK; base += 32) {
      int tl = base + trb;
      int t = t0 + tl;
      const float* hr = sm.ht[tl];
      float4 acc = make_float4(0.f, 0.f, 0.f, 0.f);
      #pragma unroll 4
      for (int n = 0; n < SDN; ++n) {
        float hn = hr[n];
        float4 cv = sm.CT[n][og];
        acc.x += hn * cv.x; acc.y += hn * cv.y;
        acc.z += hn * cv.z; acc.w += hn * cv.w;
      }
      const float4* xr = (const float4*)&sm.xs[WARM + tl][0];
      #pragma unroll 4
      for (int dd = 0; dd < DIN / 4; ++dd) {
        float4 xv = xr[dd];
        float4 d0 = sm.DT[dd * 4 + 0][og];
        float4 d1 = sm.DT[dd * 4 + 1][og];
        float4 d2 = sm.DT[dd * 4 + 2][og];
        float4 d3 = sm.DT[dd * 4 + 3][og];
        acc.x += xv.x * d0.x + xv.y * d1.x + xv.z * d2.x + xv.w * d3.x;
        acc.y += xv.x * d0.y + xv.y * d1.y + xv.z * d2.y + xv.w * d3.y;
        acc.z += xv.x * d0.z + xv.y * d1.z + xv.z * d2.z + xv.w * d3.z;
        acc.w += xv.x * d0.w + xv.y * d1.w + xv.z * d2.w + xv.w * d3.w;
      }
      ((float4*)(y + ((size_t)b * SEQL + t) * DOUT))[og] = acc;
    }
  }
}

extern "C" void kernel_launch(void* const* d_in, const int* in_sizes, int n_in,
                              void* d_out, int out_size, void* d_ws, size_t ws_size,
                              hipStream_t stream) {
  const float* x  = (const float*)d_in[0];
  const float* ll = (const float*)d_in[1];
  const float* p  = (const float*)d_in[2];
  const float* q  = (const float*)d_in[3];
  const float* B  = (const float*)d_in[4];
  const float* C  = (const float*)d_in[5];
  const float* D  = (const float*)d_in[6];
  const float* P  = (const float*)d_in[7];
  float* yo = (float*)d_out;
  float* ws = (float*)d_ws;
  setup_kernel<<<1, 256, 0, stream>>>(ll, p, q, B, P, ws);
  main_kernel<<<NBATCH * NCHUNK, BLK, 0, stream>>>(x, C, D, ws, yo);
}